// Round 4
// baseline (82.654 us; speedup 1.0000x reference)
//
#include <hip/hip_runtime.h>

#define NPTS   1024   // points per batch
#define NGRID  4096   // 64x64 grid
#define NBATCH 16
#define NCH    8      // feature channels
#define NSEG   8      // n-segments (one per wave)
#define SEGLEN (NPTS / NSEG)   // 128
#define MPT    4      // grid points per lane

// 1024 blocks x 512 threads. Block = (batch, 64-grid-point row chunk).
// Wave = one n-segment. Lane = (gp-slot 0..15) x (n-sublane 0..3);
// each lane accumulates 4 grid points over n = seg*128 + 4k + nsub.
// LDS reads: 4 distinct n per wave-iter -> distinct banks, and each
// fetched (x,y) feeds 4 grid points (4x less LDS return BW than MPT=1).
__global__ __launch_bounds__(512, 4) void rkhs_embed_kernel(
    const float* __restrict__ X,   // (16,1024,2)
    const float* __restrict__ Y,   // (16,1024,8)
    float* __restrict__ out)       // [grid: 8192][Y_grid: 16*4096*9]
{
    __shared__ float sX[NPTS * 2];     // 8 KB  (reused: sD)
    __shared__ float sY[NPTS * NCH];   // 32 KB (reused: sR partials)

    const int b     = blockIdx.x >> 6;   // 0..15
    const int chunk = blockIdx.x & 63;   // 0..63  == grid row
    const int tid   = threadIdx.x;       // 0..511
    const int seg   = tid >> 6;          // 0..7 (wave id)
    const int lane  = tid & 63;
    const int g0    = lane >> 2;         // gp slot 0..15
    const int nsub  = lane & 3;          // n sublane 0..3

    // ---- stage X,Y into LDS (float4, coalesced) ----
    const float4* Xg  = (const float4*)(X + (size_t)b * NPTS * 2);
    float4*       sX4 = (float4*)sX;
    sX4[tid] = Xg[tid];                               // 512 f4
    const float4* Yg  = (const float4*)(Y + (size_t)b * NPTS * NCH);
    float4*       sY4 = (float4*)sY;
#pragma unroll
    for (int i = 0; i < 4; ++i)
        sY4[tid + 512 * i] = Yg[tid + 512 * i];
    __syncthreads();

    const float step = 6.0f / 63.0f;
    const float gx   = -3.0f + (float)chunk * step;   // wave-uniform (row)
    float gyv[MPT];
#pragma unroll
    for (int j = 0; j < MPT; ++j)
        gyv[j] = -3.0f + (float)(g0 + 16 * j) * step;

    const float C = -2.8853900817779268f;   // -2*log2(e)

    float  dens[MPT] = {0.f, 0.f, 0.f, 0.f};
    float2 accf[MPT][4];
#pragma unroll
    for (int j = 0; j < MPT; ++j)
#pragma unroll
        for (int p = 0; p < 4; ++p) accf[j][p] = make_float2(0.f, 0.f);

    const float2* px = (const float2*)sX + seg * SEGLEN + nsub;
    const float4* py = sY4 + (size_t)(seg * SEGLEN + nsub) * 2;

#pragma unroll 4
    for (int k = 0; k < SEGLEN / 4; ++k) {            // 32 iters
        const float2 xn = px[4 * k];
        const float4 y0 = py[8 * k];
        const float4 y1 = py[8 * k + 1];

        const float dx  = gx - xn.x;
        const float dx2 = dx * dx;
#pragma unroll
        for (int j = 0; j < MPT; ++j) {
            const float dy = gyv[j] - xn.y;
            const float d2 = fmaf(dy, dy, dx2);
            const float w  = __builtin_amdgcn_exp2f(C * d2);
            dens[j] += w;
            accf[j][0].x = fmaf(w, y0.x, accf[j][0].x);
            accf[j][0].y = fmaf(w, y0.y, accf[j][0].y);
            accf[j][1].x = fmaf(w, y0.z, accf[j][1].x);
            accf[j][1].y = fmaf(w, y0.w, accf[j][1].y);
            accf[j][2].x = fmaf(w, y1.x, accf[j][2].x);
            accf[j][2].y = fmaf(w, y1.y, accf[j][2].y);
            accf[j][3].x = fmaf(w, y1.z, accf[j][3].x);
            accf[j][3].y = fmaf(w, y1.w, accf[j][3].y);
        }
    }

    // ---- reduce across the 4 n-sublanes (quad butterfly) ----
#pragma unroll
    for (int j = 0; j < MPT; ++j) {
        float r = dens[j];
        r += __shfl_xor(r, 1); r += __shfl_xor(r, 2);
        dens[j] = r;
#pragma unroll
        for (int p = 0; p < 4; ++p) {
            float a = accf[j][p].x;
            a += __shfl_xor(a, 1); a += __shfl_xor(a, 2);
            accf[j][p].x = a;
            float bb = accf[j][p].y;
            bb += __shfl_xor(bb, 1); bb += __shfl_xor(bb, 2);
            accf[j][p].y = bb;
        }
    }

    __syncthreads();                  // done reading sX/sY; safe to reuse
    float* sR = sY;                   // [8 seg][64 gp][9] = 4608 f (18 KB)
    float* sD = sX;                   // [64] densities

    if (nsub == 0) {
#pragma unroll
        for (int j = 0; j < MPT; ++j) {
            float* r = sR + ((size_t)seg * 64 + (g0 + 16 * j)) * 9;
            r[0] = dens[j];
#pragma unroll
            for (int p = 0; p < 4; ++p) {
                r[1 + 2 * p] = accf[j][p].x;
                r[2 + 2 * p] = accf[j][p].y;
            }
        }
    }

    if (b == 0 && tid < 64) {         // grid coords (row=chunk, col=tid)
        const int m = chunk * 64 + tid;
        out[2 * m]     = gx;
        out[2 * m + 1] = -3.0f + (float)tid * step;
    }
    __syncthreads();

    // phase 1: density per grid point
    if (tid < 64) {
        float d = 0.f;
#pragma unroll
        for (int s = 0; s < NSEG; ++s) d += sR[((size_t)s * 64 + tid) * 9];
        sD[tid] = d;
        out[(size_t)NGRID * 2 + ((size_t)b * NGRID + chunk * 64 + tid) * 9] = d;
    }
    __syncthreads();

    // phase 2: 512 threads cover (gp 0..63) x (c 1..8)
    {
        const int gp = tid >> 3;
        const int c  = (tid & 7) + 1;
        float f = 0.f;
#pragma unroll
        for (int s = 0; s < NSEG; ++s) f += sR[((size_t)s * 64 + gp) * 9 + c];
        const float inv = 1.0f / (sD[gp] + 1e-6f);
        out[(size_t)NGRID * 2 + ((size_t)b * NGRID + chunk * 64 + gp) * 9 + c] = f * inv;
    }
}

extern "C" void kernel_launch(void* const* d_in, const int* in_sizes, int n_in,
                              void* d_out, int out_size, void* d_ws, size_t ws_size,
                              hipStream_t stream) {
    const float* X = (const float*)d_in[0];   // (16,1024,2) fp32
    const float* Y = (const float*)d_in[1];   // (16,1024,8) fp32
    float* out = (float*)d_out;

    dim3 grid(NBATCH * 64);                   // 1024 blocks
    dim3 block(512);
    rkhs_embed_kernel<<<grid, block, 0, stream>>>(X, Y, out);
}